// Round 1
// baseline (39.771 us; speedup 1.0000x reference)
//
#include <hip/hip_runtime.h>
#include <math.h>

#define B_SZ   2048
#define D_SZ   4096
#define O_SZ   3
#define NBASIS 8
#define TB     16            // batch rows per block
#define NC     16            // d-chunks
#define DC     (D_SZ / NC)   // 256 d's per chunk

// ws layout:
//   effc_t : NC*NBASIS*DC float4  = 524288 B   (chunk-transposed [c][n][dl], o in .x/.y/.z)
//   effb   : D_SZ float4          =  65536 B
//   partial: NC*B_SZ*3 float      = 393216 B
#define WS_EFFC_BYTES  (NC * NBASIS * DC * 16)
#define WS_EFFB_BYTES  (D_SZ * 16)
#define WS_PART_BYTES  (NC * B_SZ * 3 * 4)

// ---------------------------------------------------------------------------
// Precompute effective coefficients: effc[d][n][o] = coef[d][o][n]*ssp[d][o]*mask
// stored as [chunk][n][d_in_chunk] float4; effb[d][o] = sb[d][o]*mask.
__global__ __launch_bounds__(256) void precompute_eff(
    const float* __restrict__ coef, const float* __restrict__ sb,
    const float* __restrict__ ssp,  const float* __restrict__ mask,
    float4* __restrict__ effc_t, float4* __restrict__ effb)
{
    int d = blockIdx.x * 256 + threadIdx.x;
    if (d >= D_SZ) return;
    float m0 = mask[d*3+0], m1 = mask[d*3+1], m2 = mask[d*3+2];
    float s0 = ssp[d*3+0]*m0, s1 = ssp[d*3+1]*m1, s2 = ssp[d*3+2]*m2;
    int c  = d >> 8;        // chunk (DC==256)
    int dl = d & (DC - 1);
    #pragma unroll
    for (int n = 0; n < NBASIS; ++n) {
        float4 v;
        v.x = coef[(d*3+0)*NBASIS + n] * s0;
        v.y = coef[(d*3+1)*NBASIS + n] * s1;
        v.z = coef[(d*3+2)*NBASIS + n] * s2;
        v.w = 0.0f;
        effc_t[(c*NBASIS + n)*DC + dl] = v;
    }
    float4 bv;
    bv.x = sb[d*3+0]*m0; bv.y = sb[d*3+1]*m1; bv.z = sb[d*3+2]*m2; bv.w = 0.0f;
    effb[d] = bv;
}

// ---------------------------------------------------------------------------
// Main kernel: block (bg, dc) covers b in [bg*TB, bg*TB+TB), d in [dc*DC, dc*DC+DC).
// One d per thread; 16 b's per thread; coef chunk staged in LDS.
__global__ __launch_bounds__(256) void kan_main(
    const float* __restrict__ x, const float4* __restrict__ effc_t,
    const float4* __restrict__ effb, const float* __restrict__ grid,
    float* __restrict__ partial)
{
    __shared__ float4 effc[NBASIS * DC];   // 32 KB, reused for reduction

    const int tid = threadIdx.x;
    const int bg  = blockIdx.x;            // 0 .. B_SZ/TB-1
    const int dc  = blockIdx.y;            // 0 .. NC-1
    const int d   = dc * DC + tid;

    // stage coef chunk (coalesced global, conflict-free LDS writes)
    #pragma unroll
    for (int i = 0; i < NBASIS; ++i)
        effc[i * DC + tid] = effc_t[(dc * NBASIS + i) * DC + tid];

    const float g3   = grid[3];                       // -1
    const float invh = 1.0f / (grid[4] - grid[3]);    // 2.5
    const float4 eb  = effb[d];
    __syncthreads();

    float acc[TB][3];
    #pragma unroll
    for (int q = 0; q < TB; ++q) { acc[q][0] = 0.f; acc[q][1] = 0.f; acc[q][2] = 0.f; }

    const int b0 = bg * TB;
    const float* xp = x + (size_t)b0 * D_SZ + d;

    #pragma unroll
    for (int q = 0; q < TB; ++q) {
        float xv = xp[(size_t)q * D_SZ];
        // uniform cubic B-spline, closed form
        float u  = (xv - g3) * invh;
        float cf = floorf(u);
        cf = fminf(fmaxf(cf, 0.0f), 4.0f);
        int  cell = (int)cf;
        float t  = u - cf;
        float t2 = t * t, t3 = t2 * t;
        float omt = 1.0f - t;
        float w0 = omt * omt * omt * (1.0f/6.0f);
        float w1 = (3.0f*t3 - 6.0f*t2 + 4.0f) * (1.0f/6.0f);
        float w2 = (-3.0f*t3 + 3.0f*t2 + 3.0f*t + 1.0f) * (1.0f/6.0f);
        float w3 = t3 * (1.0f/6.0f);
        float sil = xv / (1.0f + __expf(-xv));

        const float4* cp = &effc[cell * DC + tid];
        float4 c0 = cp[0];
        float4 c1 = cp[DC];
        float4 c2 = cp[2*DC];
        float4 c3 = cp[3*DC];
        acc[q][0] += w0*c0.x + w1*c1.x + w2*c2.x + w3*c3.x + sil*eb.x;
        acc[q][1] += w0*c0.y + w1*c1.y + w2*c2.y + w3*c3.y + sil*eb.y;
        acc[q][2] += w0*c0.z + w1*c1.z + w2*c2.z + w3*c3.z + sil*eb.z;
    }

    // block reduction over the 256 d's, 24 values at a time (fits reused 32 KB LDS)
    float* red = (float*)effc;   // 8192 floats
    #pragma unroll
    for (int half = 0; half < 2; ++half) {
        __syncthreads();   // previous LDS use finished
        #pragma unroll
        for (int q = 0; q < TB/2; ++q)
            #pragma unroll
            for (int o = 0; o < 3; ++o)
                red[(q*3 + o) * DC + tid] = acc[half*(TB/2) + q][o];
        __syncthreads();
        #pragma unroll
        for (int s = 128; s >= 1; s >>= 1) {
            for (int w = tid; w < 24 * s; w += 256) {
                int row = w / s, tt = w % s;   // s is compile-time (unrolled)
                red[row * DC + tt] += red[row * DC + tt + s];
            }
            __syncthreads();
        }
        if (tid < 24) {
            int q = tid / 3, o = tid % 3;
            int b = b0 + half*(TB/2) + q;
            partial[((size_t)dc * B_SZ + b) * 3 + o] = red[tid * DC];
        }
    }
}

// ---------------------------------------------------------------------------
__global__ __launch_bounds__(256) void reduce_partials(
    const float* __restrict__ partial, float* __restrict__ out)
{
    int i = blockIdx.x * 256 + threadIdx.x;
    if (i >= B_SZ * 3) return;
    float s = 0.0f;
    #pragma unroll
    for (int c = 0; c < NC; ++c) s += partial[(size_t)c * B_SZ * 3 + i];
    out[i] = s;
}

// ---------------------------------------------------------------------------
// Fallback (no workspace): block per b, raw arrays. Slower but correct.
__global__ __launch_bounds__(256) void kan_fallback(
    const float* __restrict__ x, const float* __restrict__ grid,
    const float* __restrict__ coef, const float* __restrict__ sb,
    const float* __restrict__ ssp,  const float* __restrict__ mask,
    float* __restrict__ out)
{
    __shared__ float red[3][4];
    int b = blockIdx.x, tid = threadIdx.x;
    float g3 = grid[3], invh = 1.0f / (grid[4] - grid[3]);
    float acc[3] = {0.f, 0.f, 0.f};
    for (int i = 0; i < D_SZ / 256; ++i) {
        int d = i * 256 + tid;
        float xv = x[(size_t)b * D_SZ + d];
        float u  = (xv - g3) * invh;
        float cf = floorf(u);
        cf = fminf(fmaxf(cf, 0.0f), 4.0f);
        int  cell = (int)cf;
        float t  = u - cf;
        float t2 = t * t, t3 = t2 * t;
        float omt = 1.0f - t;
        float w0 = omt*omt*omt * (1.0f/6.0f);
        float w1 = (3.0f*t3 - 6.0f*t2 + 4.0f) * (1.0f/6.0f);
        float w2 = (-3.0f*t3 + 3.0f*t2 + 3.0f*t + 1.0f) * (1.0f/6.0f);
        float w3 = t3 * (1.0f/6.0f);
        float sil = xv / (1.0f + __expf(-xv));
        #pragma unroll
        for (int o = 0; o < 3; ++o) {
            const float* cp = &coef[(d*3 + o) * NBASIS + cell];
            float s = w0*cp[0] + w1*cp[1] + w2*cp[2] + w3*cp[3];
            float m = mask[d*3 + o];
            acc[o] += s * ssp[d*3 + o] * m + sil * sb[d*3 + o] * m;
        }
    }
    int lane = tid & 63, wv = tid >> 6;
    #pragma unroll
    for (int o = 0; o < 3; ++o) {
        float v = acc[o];
        #pragma unroll
        for (int off = 32; off >= 1; off >>= 1) v += __shfl_down(v, off, 64);
        if (lane == 0) red[o][wv] = v;
    }
    __syncthreads();
    if (tid < 3) {
        float s = red[tid][0] + red[tid][1] + red[tid][2] + red[tid][3];
        out[b * 3 + tid] = s;
    }
}

// ---------------------------------------------------------------------------
extern "C" void kernel_launch(void* const* d_in, const int* in_sizes, int n_in,
                              void* d_out, int out_size, void* d_ws, size_t ws_size,
                              hipStream_t stream)
{
    const float* x    = (const float*)d_in[0];
    const float* grid = (const float*)d_in[4];
    const float* coef = (const float*)d_in[5];
    const float* sb   = (const float*)d_in[6];
    const float* ssp  = (const float*)d_in[7];
    const float* mask = (const float*)d_in[8];
    float* out = (float*)d_out;

    size_t need = (size_t)WS_EFFC_BYTES + WS_EFFB_BYTES + WS_PART_BYTES;
    if (ws_size >= need) {
        float4* effc_t  = (float4*)d_ws;
        float4* effb    = (float4*)((char*)d_ws + WS_EFFC_BYTES);
        float*  partial = (float*)((char*)d_ws + WS_EFFC_BYTES + WS_EFFB_BYTES);

        precompute_eff<<<D_SZ/256, 256, 0, stream>>>(coef, sb, ssp, mask, effc_t, effb);
        dim3 g(B_SZ / TB, NC);
        kan_main<<<g, 256, 0, stream>>>(x, effc_t, effb, grid, partial);
        reduce_partials<<<(B_SZ*3 + 255)/256, 256, 0, stream>>>(partial, out);
    } else {
        kan_fallback<<<B_SZ, 256, 0, stream>>>(x, grid, coef, sb, ssp, mask, out);
    }
}